// Round 1
// baseline (7612.469 us; speedup 1.0000x reference)
//
#include <hip/hip_runtime.h>
#include <hip/hip_bf16.h>

#define BB 16
#define SS 512
#define DD 1024
#define HH 16
#define LL 4
#define DHH 64

typedef __attribute__((ext_vector_type(8))) short short8;
typedef __attribute__((ext_vector_type(4))) float f32x4;

__device__ __forceinline__ unsigned short f2bf(float f) {
  union { float f; unsigned int u; } v; v.f = f;
  unsigned int r = v.u + 0x7FFFu + ((v.u >> 16) & 1u);
  return (unsigned short)(r >> 16);
}

__device__ __forceinline__ float wave_max(float v) {
#pragma unroll
  for (int off = 32; off > 0; off >>= 1) v = fmaxf(v, __shfl_xor(v, off));
  return v;
}
__device__ __forceinline__ float wave_sum(float v) {
#pragma unroll
  for (int off = 32; off > 0; off >>= 1) v += __shfl_xor(v, off);
  return v;
}

// ---------------- q0 = x + positional encoding ----------------
__global__ __launch_bounds__(256) void k_add_pe(const float* __restrict__ x,
                                                float* __restrict__ out) {
  size_t idx = (size_t)blockIdx.x * 256 + threadIdx.x;
  int d = (int)(idx & (DD - 1));
  int s = (int)((idx >> 10) & (SS - 1));
  int ip = d >> 1;
  // exp(2i * (-ln(10000)/1024)) ; -2*ln(1e4)/1024 = -0.017988946
  float freq = expf((float)ip * -0.017988946039016f);
  float ang = (float)s * freq;
  float pe = (d & 1) ? cosf(ang) : sinf(ang);
  out[idx] = x[idx] + pe;
}

// ---------------- C[M,N] = A[M,K] @ W[N,K]^T + bias, bf16 MFMA ----------------
__global__ __launch_bounds__(256) void k_gemm_bt_bias(
    const float* __restrict__ A, const float* __restrict__ W,
    const float* __restrict__ bias, float* __restrict__ C,
    int M, int N, int K) {
  // 64x64 tile, 4 waves in 2x2, each wave 32x32 via 2x2 mfma_16x16x32 frags.
  // +8 ushort row pad: row stride 80B -> frag-read conflicts drop to ~2-way (free).
  __shared__ unsigned short As[64][40];
  __shared__ unsigned short Bs[64][40];
  const int tid = threadIdx.x;
  const int lane = tid & 63;
  const int w = tid >> 6;
  const int wr = w >> 1, wc = w & 1;
  const int bm = blockIdx.x * 64, bn = blockIdx.y * 64;
  const int lr = tid >> 2;             // 0..63 staging row
  const int lc = (tid & 3) << 3;       // 0,8,16,24 staging k-col
  const int fr = lane & 15, fq = lane >> 4;

  f32x4 acc[2][2] = {};

  const float* ag = A + (size_t)(bm + lr) * K + lc;
  const float* wg = W + (size_t)(bn + lr) * K + lc;

  for (int k0 = 0; k0 < K; k0 += 32) {
    float4 a0 = *(const float4*)(ag + k0);
    float4 a1 = *(const float4*)(ag + k0 + 4);
    float4 w0 = *(const float4*)(wg + k0);
    float4 w1 = *(const float4*)(wg + k0 + 4);
    short8 ap, wp;
    ap[0] = (short)f2bf(a0.x); ap[1] = (short)f2bf(a0.y);
    ap[2] = (short)f2bf(a0.z); ap[3] = (short)f2bf(a0.w);
    ap[4] = (short)f2bf(a1.x); ap[5] = (short)f2bf(a1.y);
    ap[6] = (short)f2bf(a1.z); ap[7] = (short)f2bf(a1.w);
    wp[0] = (short)f2bf(w0.x); wp[1] = (short)f2bf(w0.y);
    wp[2] = (short)f2bf(w0.z); wp[3] = (short)f2bf(w0.w);
    wp[4] = (short)f2bf(w1.x); wp[5] = (short)f2bf(w1.y);
    wp[6] = (short)f2bf(w1.z); wp[7] = (short)f2bf(w1.w);
    *(short8*)(&As[lr][lc]) = ap;
    *(short8*)(&Bs[lr][lc]) = wp;
    __syncthreads();

    // A frag: lane holds A[row=fr][k=8*fq+e]; B frag: B[k=8*fq+e][col=fr] = W[col][k]
    short8 af0 = *(const short8*)(&As[wr * 32 + fr][fq * 8]);
    short8 af1 = *(const short8*)(&As[wr * 32 + 16 + fr][fq * 8]);
    short8 bf0 = *(const short8*)(&Bs[wc * 32 + fr][fq * 8]);
    short8 bf1 = *(const short8*)(&Bs[wc * 32 + 16 + fr][fq * 8]);
    acc[0][0] = __builtin_amdgcn_mfma_f32_16x16x32_bf16(af0, bf0, acc[0][0], 0, 0, 0);
    acc[0][1] = __builtin_amdgcn_mfma_f32_16x16x32_bf16(af0, bf1, acc[0][1], 0, 0, 0);
    acc[1][0] = __builtin_amdgcn_mfma_f32_16x16x32_bf16(af1, bf0, acc[1][0], 0, 0, 0);
    acc[1][1] = __builtin_amdgcn_mfma_f32_16x16x32_bf16(af1, bf1, acc[1][1], 0, 0, 0);
    __syncthreads();
  }

#pragma unroll
  for (int m = 0; m < 2; ++m)
#pragma unroll
    for (int n = 0; n < 2; ++n) {
      int row = bm + wr * 32 + m * 16 + fq * 4;   // C/D: col=lane&15, row=(lane>>4)*4+r
      int col = bn + wc * 32 + n * 16 + fr;
      float bb = bias[col];
#pragma unroll
      for (int r = 0; r < 4; ++r)
        C[(size_t)(row + r) * N + col] = acc[m][n][r] + bb;
    }
}

// ---------------- fused attention: one wave per query row ----------------
__global__ __launch_bounds__(256) void k_attn(
    const float* __restrict__ QK, const float* __restrict__ V,
    const float* __restrict__ gam, float* __restrict__ AO,
    float* __restrict__ scores_out) {
  __shared__ float qs[4][DHH];
  __shared__ float arr[4][SS];
  const int tid = threadIdx.x;
  const int lane = tid & 63;
  const int w = tid >> 6;
  const int itile = blockIdx.x & (SS / 4 - 1);
  const int bh = blockIdx.x >> 7;
  const int b = bh >> 4;
  const int h = bh & (HH - 1);
  const int i = itile * 4 + w;

  const float* Qb = QK + (size_t)b * SS * DD + (size_t)h * DHH;  // row j at Qb + j*DD
  const float* Vb = V + (size_t)b * SS * DD + (size_t)h * DHH;
  const float gneg = -fabsf(gam[h]);

  qs[w][lane] = Qb[(size_t)i * DD + lane];
  __syncthreads();

  const float4* qs4 = (const float4*)(&qs[w][0]);
  const int jb = lane << 3;  // lane owns j in [jb, jb+8)

  float sc[8];
#pragma unroll
  for (int c = 0; c < 8; ++c) {
    const int j = jb + c;
    if (j < i) {
      const float4* kr = (const float4*)(Qb + (size_t)j * DD);
      float dot = 0.0f;
#pragma unroll
      for (int d4 = 0; d4 < 16; ++d4) {
        float4 kv = kr[d4];
        float4 qv = qs4[d4];
        dot = fmaf(kv.x, qv.x, dot); dot = fmaf(kv.y, qv.y, dot);
        dot = fmaf(kv.z, qv.z, dot); dot = fmaf(kv.w, qv.w, dot);
      }
      sc[c] = dot * 0.125f;  // 1/sqrt(64)
    } else {
      sc[c] = -1e30f;
    }
  }

  // softmax #1 (for distance weights)
  float m1 = sc[0];
#pragma unroll
  for (int c = 1; c < 8; ++c) m1 = fmaxf(m1, sc[c]);
  m1 = wave_max(m1);
  float p[8];
  float lsum = 0.0f;
#pragma unroll
  for (int c = 0; c < 8; ++c) {
    p[c] = (jb + c < i) ? expf(sc[c] - m1) : 0.0f;
    lsum += p[c];
  }
  float tot = wave_sum(lsum);
  float inv = 1.0f / tot;  // i==0: inf; all downstream NaN are predicated away

  // inclusive cumsum: lane-local prefix + exclusive lane-scan
  float xs = lsum;
#pragma unroll
  for (int off = 1; off < 64; off <<= 1) {
    float y = __shfl_up(xs, off);
    if (lane >= off) xs += y;
  }
  float run = xs - lsum;  // exclusive prefix of this lane's chunk

  float s2[8];
#pragma unroll
  for (int c = 0; c < 8; ++c) {
    run += p[c];
    float cum = run * inv;
    float dist = sqrtf(fmaxf((1.0f - cum) * (float)(i - (jb + c)), 0.0f));
    float te = expf(gneg * dist);
    te = fminf(fmaxf(te, 1e-5f), 1e5f);
    s2[c] = sc[c] * te;
  }

  // softmax #2 + maxout rescale
  float m2 = s2[0];
#pragma unroll
  for (int c = 1; c < 8; ++c) m2 = fmaxf(m2, s2[c]);
  m2 = wave_max(m2);
  float e[8];
  float lsum2 = 0.0f;
#pragma unroll
  for (int c = 0; c < 8; ++c) {
    e[c] = (jb + c < i) ? expf(s2[c] - m2) : 0.0f;
    lsum2 += e[c];
  }
  float tot2 = wave_sum(lsum2);
  // attn = e/tot2; max attn = 1/tot2; scale = min(tot2, 5); attn *= scale/1
  float mult = fminf(tot2, 5.0f) / tot2;

  float av[8];
#pragma unroll
  for (int c = 0; c < 8; ++c) {
    av[c] = (jb + c < i) ? e[c] * mult : 0.0f;
    arr[w][jb + c] = av[c];
  }
  if (scores_out) {
    float* srow = scores_out + ((size_t)(b * HH + h) * SS + i) * SS + jb;
    *(float4*)(srow) = make_float4(av[0], av[1], av[2], av[3]);
    *(float4*)(srow + 4) = make_float4(av[4], av[5], av[6], av[7]);
  }
  __syncthreads();

  // PV: lane = head dim; serial over valid j
  float acc = 0.0f;
  const float* arw = arr[w];
  const float* vcol = Vb + lane;
  int j = 0;
  for (; j + 4 <= i; j += 4) {
    acc = fmaf(arw[j], vcol[(size_t)(j)*DD], acc);
    acc = fmaf(arw[j + 1], vcol[(size_t)(j + 1) * DD], acc);
    acc = fmaf(arw[j + 2], vcol[(size_t)(j + 2) * DD], acc);
    acc = fmaf(arw[j + 3], vcol[(size_t)(j + 3) * DD], acc);
  }
  for (; j < i; ++j) acc = fmaf(arw[j], vcol[(size_t)j * DD], acc);

  AO[(size_t)b * SS * DD + (size_t)i * DD + (size_t)h * DHH + lane] = acc;
}

// ---------------- residual + layernorm (r may be null) ----------------
__global__ __launch_bounds__(256) void k_res_ln(
    const float* __restrict__ x, const float* __restrict__ r,
    const float* __restrict__ w, const float* __restrict__ b,
    float* __restrict__ out) {
  __shared__ float red[4];
  const int row = blockIdx.x;
  const int tid = threadIdx.x;
  const int lane = tid & 63, wv = tid >> 6;
  float4 y = ((const float4*)(x + (size_t)row * DD))[tid];
  if (r) {
    float4 rr = ((const float4*)(r + (size_t)row * DD))[tid];
    y.x += rr.x; y.y += rr.y; y.z += rr.z; y.w += rr.w;
  }
  float s = y.x + y.y + y.z + y.w;
  s = wave_sum(s);
  if (lane == 0) red[wv] = s;
  __syncthreads();
  float mean = (red[0] + red[1] + red[2] + red[3]) * (1.0f / DD);
  __syncthreads();
  float d0 = y.x - mean, d1 = y.y - mean, d2 = y.z - mean, d3 = y.w - mean;
  float s2 = d0 * d0 + d1 * d1 + d2 * d2 + d3 * d3;
  s2 = wave_sum(s2);
  if (lane == 0) red[wv] = s2;
  __syncthreads();
  float var = (red[0] + red[1] + red[2] + red[3]) * (1.0f / DD);
  float rstd = rsqrtf(var + 1e-5f);
  float4 ww = ((const float4*)w)[tid];
  float4 bb = ((const float4*)b)[tid];
  float4 o;
  o.x = d0 * rstd * ww.x + bb.x;
  o.y = d1 * rstd * ww.y + bb.y;
  o.z = d2 * rstd * ww.z + bb.z;
  o.w = d3 * rstd * ww.w + bb.w;
  ((float4*)(out + (size_t)row * DD))[tid] = o;
}

extern "C" void kernel_launch(void* const* d_in, const int* in_sizes, int n_in,
                              void* d_out, int out_size, void* d_ws, size_t ws_size,
                              hipStream_t stream) {
  (void)in_sizes; (void)n_in; (void)out_size; (void)ws_size;
  const float* x = (const float*)d_in[0];
  // d_in[1] = lens, unused in eval mode
  const float* Wq = (const float*)d_in[2];
  const float* bq = (const float*)d_in[3];
  const float* Wv = (const float*)d_in[4];
  const float* bv = (const float*)d_in[5];
  const float* Wo = (const float*)d_in[6];
  const float* bo = (const float*)d_in[7];
  const float* gam = (const float*)d_in[8];
  const float* lnw = (const float*)d_in[9];
  const float* lnb = (const float*)d_in[10];
  const float* flnw = (const float*)d_in[11];
  const float* flnb = (const float*)d_in[12];

  float* out0 = (float*)d_out;                       // [B,S,D] final LN
  float* scores = out0 + (size_t)BB * SS * DD;       // [B,H,S,S] last-layer attn
  const size_t BUF = (size_t)BB * SS * DD;           // 8.4M floats
  float* ws = (float*)d_ws;
  float* A = ws;            // activation in
  float* t1 = ws + BUF;     // qlin / proj
  float* t2 = ws + 2 * BUF; // vlin / act out
  float* t3 = out0;         // AO (d_out region0 doubles as scratch)

  const int M = BB * SS;  // 8192

  k_add_pe<<<dim3(BB * SS * DD / 256), 256, 0, stream>>>(x, A);

  for (int l = 0; l < LL; ++l) {
    const float* wq = Wq + (size_t)l * DD * DD;
    const float* wv_ = Wv + (size_t)l * DD * DD;
    const float* wo_ = Wo + (size_t)l * DD * DD;
    k_gemm_bt_bias<<<dim3(M / 64, DD / 64), 256, 0, stream>>>(A, wq, bq + l * DD, t1, M, DD, DD);
    k_gemm_bt_bias<<<dim3(M / 64, DD / 64), 256, 0, stream>>>(A, wv_, bv + l * DD, t2, M, DD, DD);
    k_attn<<<dim3(BB * HH * SS / 4), 256, 0, stream>>>(t1, t2, gam + l * HH, t3,
                                                       (l == LL - 1) ? scores : nullptr);
    k_gemm_bt_bias<<<dim3(M / 64, DD / 64), 256, 0, stream>>>(t3, wo_, bo + l * DD, t1, M, DD, DD);
    k_res_ln<<<dim3(M), 256, 0, stream>>>(A, t1, lnw + l * DD, lnb + l * DD, t2);
    float* oldA = A; A = t2; t2 = t1; t1 = oldA;  // rotate scratch
  }
  k_res_ln<<<dim3(M), 256, 0, stream>>>(A, nullptr, flnw, flnb, out0);
}

// Round 2
// 1948.201 us; speedup vs baseline: 3.9074x; 3.9074x over previous
//
#include <hip/hip_runtime.h>
#include <hip/hip_bf16.h>

#define BB 16
#define SS 512
#define DD 1024
#define HH 16
#define LL 4
#define DHH 64

typedef __attribute__((ext_vector_type(8))) short short8;
typedef __attribute__((ext_vector_type(4))) float f32x4;

__device__ __forceinline__ unsigned short f2bf(float f) {
  union { float f; unsigned int u; } v; v.f = f;
  unsigned int r = v.u + 0x7FFFu + ((v.u >> 16) & 1u);
  return (unsigned short)(r >> 16);
}

__device__ __forceinline__ float wave_max(float v) {
#pragma unroll
  for (int off = 32; off > 0; off >>= 1) v = fmaxf(v, __shfl_xor(v, off));
  return v;
}
__device__ __forceinline__ float wave_sum(float v) {
#pragma unroll
  for (int off = 32; off > 0; off >>= 1) v += __shfl_xor(v, off);
  return v;
}

// ---------------- q0 = x + positional encoding ----------------
__global__ __launch_bounds__(256) void k_add_pe(const float* __restrict__ x,
                                                float* __restrict__ out) {
  size_t idx = (size_t)blockIdx.x * 256 + threadIdx.x;
  int d = (int)(idx & (DD - 1));
  int s = (int)((idx >> 10) & (SS - 1));
  int ip = d >> 1;
  float freq = expf((float)ip * -0.017988946039016f);
  float ang = (float)s * freq;
  float pe = (d & 1) ? cosf(ang) : sinf(ang);
  out[idx] = x[idx] + pe;
}

// ---------------- C[M,N] = A[M,K] @ W[N,K]^T + bias, bf16 MFMA ----------------
__global__ __launch_bounds__(256) void k_gemm_bt_bias(
    const float* __restrict__ A, const float* __restrict__ W,
    const float* __restrict__ bias, float* __restrict__ C,
    int M, int N, int K) {
  __shared__ unsigned short As[64][40];
  __shared__ unsigned short Bs[64][40];
  const int tid = threadIdx.x;
  const int lane = tid & 63;
  const int w = tid >> 6;
  const int wr = w >> 1, wc = w & 1;
  const int bm = blockIdx.x * 64, bn = blockIdx.y * 64;
  const int lr = tid >> 2;
  const int lc = (tid & 3) << 3;
  const int fr = lane & 15, fq = lane >> 4;

  f32x4 acc[2][2] = {};

  const float* ag = A + (size_t)(bm + lr) * K + lc;
  const float* wg = W + (size_t)(bn + lr) * K + lc;

  for (int k0 = 0; k0 < K; k0 += 32) {
    float4 a0 = *(const float4*)(ag + k0);
    float4 a1 = *(const float4*)(ag + k0 + 4);
    float4 w0 = *(const float4*)(wg + k0);
    float4 w1 = *(const float4*)(wg + k0 + 4);
    short8 ap, wp;
    ap[0] = (short)f2bf(a0.x); ap[1] = (short)f2bf(a0.y);
    ap[2] = (short)f2bf(a0.z); ap[3] = (short)f2bf(a0.w);
    ap[4] = (short)f2bf(a1.x); ap[5] = (short)f2bf(a1.y);
    ap[6] = (short)f2bf(a1.z); ap[7] = (short)f2bf(a1.w);
    wp[0] = (short)f2bf(w0.x); wp[1] = (short)f2bf(w0.y);
    wp[2] = (short)f2bf(w0.z); wp[3] = (short)f2bf(w0.w);
    wp[4] = (short)f2bf(w1.x); wp[5] = (short)f2bf(w1.y);
    wp[6] = (short)f2bf(w1.z); wp[7] = (short)f2bf(w1.w);
    *(short8*)(&As[lr][lc]) = ap;
    *(short8*)(&Bs[lr][lc]) = wp;
    __syncthreads();

    short8 af0 = *(const short8*)(&As[wr * 32 + fr][fq * 8]);
    short8 af1 = *(const short8*)(&As[wr * 32 + 16 + fr][fq * 8]);
    short8 bf0 = *(const short8*)(&Bs[wc * 32 + fr][fq * 8]);
    short8 bf1 = *(const short8*)(&Bs[wc * 32 + 16 + fr][fq * 8]);
    acc[0][0] = __builtin_amdgcn_mfma_f32_16x16x32_bf16(af0, bf0, acc[0][0], 0, 0, 0);
    acc[0][1] = __builtin_amdgcn_mfma_f32_16x16x32_bf16(af0, bf1, acc[0][1], 0, 0, 0);
    acc[1][0] = __builtin_amdgcn_mfma_f32_16x16x32_bf16(af1, bf0, acc[1][0], 0, 0, 0);
    acc[1][1] = __builtin_amdgcn_mfma_f32_16x16x32_bf16(af1, bf1, acc[1][1], 0, 0, 0);
    __syncthreads();
  }

#pragma unroll
  for (int m = 0; m < 2; ++m)
#pragma unroll
    for (int n = 0; n < 2; ++n) {
      int row = bm + wr * 32 + m * 16 + fq * 4;
      int col = bn + wc * 32 + n * 16 + fr;
      float bb = bias[col];
#pragma unroll
      for (int r = 0; r < 4; ++r)
        C[(size_t)(row + r) * N + col] = acc[m][n][r] + bb;
    }
}

// ---------------- fused MFMA attention ----------------
// Block: one (b,h), 64-row i-tile. 8 waves (512 thr): wr=w&3 row-block(16),
// wc=w>>2 col-half(32). Full fp32 score rows in LDS (needed by the
// softmax->cumsum->dist->softmax->maxout chain); attn written back in-place
// as bf16 (same row base, stride keeps rows disjoint) to feed PV A-frags.
__global__ __launch_bounds__(512) void k_attn_mfma(
    const float* __restrict__ QK, const float* __restrict__ V,
    const float* __restrict__ gam, float* __restrict__ AO,
    float* __restrict__ scores_out) {
  __shared__ float sc_s[64][516];          // 132096 B, stride 516 f (2-way frag reads)
  __shared__ unsigned short Qs[64][72];    // 9216 B
  __shared__ unsigned short Ks[64][72];    // 9216 B
  __shared__ unsigned short Vt[64][72];    // 9216 B  (total 156 KB -> 1 blk/CU)

  const int tid = threadIdx.x;
  const int lane = tid & 63;
  const int w = tid >> 6;
  const int wr = w & 3;
  const int wc = w >> 2;
  const int fr = lane & 15, fq = lane >> 4;

  const int itile = blockIdx.x & 7;
  const int bh = blockIdx.x >> 3;
  const int b = bh >> 4;
  const int h = bh & 15;
  const int i0 = itile * 64;
  const int njt = itile + 1;
  const int jmax = njt * 64;

  const float* Qb = QK + (size_t)b * SS * DD + (size_t)h * DHH;
  const float* Vb = V + (size_t)b * SS * DD + (size_t)h * DHH;
  const float gneg = -fabsf(gam[h]);

  const int srow = tid >> 3;             // staging row 0..63
  const int sdb = (tid & 7) * 8;         // staging d-block

  // stage Q tile (bf16)
  {
    const float* src = Qb + (size_t)(i0 + srow) * DD + sdb;
    float4 f0 = *(const float4*)(src);
    float4 f1 = *(const float4*)(src + 4);
    short8 pk;
    pk[0] = (short)f2bf(f0.x); pk[1] = (short)f2bf(f0.y);
    pk[2] = (short)f2bf(f0.z); pk[3] = (short)f2bf(f0.w);
    pk[4] = (short)f2bf(f1.x); pk[5] = (short)f2bf(f1.y);
    pk[6] = (short)f2bf(f1.z); pk[7] = (short)f2bf(f1.w);
    *(short8*)&Qs[srow][sdb] = pk;
  }

  // ---- QK^T into sc_s (scaled + causally masked) ----
  for (int jt = 0; jt < njt; ++jt) {
    {
      const float* src = Qb + (size_t)(jt * 64 + srow) * DD + sdb;  // K == Q
      float4 f0 = *(const float4*)(src);
      float4 f1 = *(const float4*)(src + 4);
      short8 pk;
      pk[0] = (short)f2bf(f0.x); pk[1] = (short)f2bf(f0.y);
      pk[2] = (short)f2bf(f0.z); pk[3] = (short)f2bf(f0.w);
      pk[4] = (short)f2bf(f1.x); pk[5] = (short)f2bf(f1.y);
      pk[6] = (short)f2bf(f1.z); pk[7] = (short)f2bf(f1.w);
      *(short8*)&Ks[srow][sdb] = pk;
    }
    __syncthreads();

    short8 a0 = *(const short8*)&Qs[wr * 16 + fr][fq * 8];
    short8 a1 = *(const short8*)&Qs[wr * 16 + fr][32 + fq * 8];
    short8 b00 = *(const short8*)&Ks[wc * 32 + fr][fq * 8];
    short8 b01 = *(const short8*)&Ks[wc * 32 + fr][32 + fq * 8];
    short8 b10 = *(const short8*)&Ks[wc * 32 + 16 + fr][fq * 8];
    short8 b11 = *(const short8*)&Ks[wc * 32 + 16 + fr][32 + fq * 8];
    f32x4 s0 = {}, s1 = {};
    s0 = __builtin_amdgcn_mfma_f32_16x16x32_bf16(a0, b00, s0, 0, 0, 0);
    s0 = __builtin_amdgcn_mfma_f32_16x16x32_bf16(a1, b01, s0, 0, 0, 0);
    s1 = __builtin_amdgcn_mfma_f32_16x16x32_bf16(a0, b10, s1, 0, 0, 0);
    s1 = __builtin_amdgcn_mfma_f32_16x16x32_bf16(a1, b11, s1, 0, 0, 0);

#pragma unroll
    for (int n = 0; n < 2; ++n) {
      const int j = jt * 64 + wc * 32 + n * 16 + fr;
#pragma unroll
      for (int r = 0; r < 4; ++r) {
        const int row = wr * 16 + fq * 4 + r;
        const float val = (n ? s1[r] : s0[r]) * 0.125f;
        sc_s[row][j] = (j < i0 + row) ? val : -1e30f;
      }
    }
    __syncthreads();
  }

  // ---- softmax -> cumsum -> dist-decay -> softmax -> maxout, per row ----
  // wave w handles rows w*8 .. w*8+7
  const int jb = lane << 3;
  for (int q = 0; q < 8; ++q) {
    const int r_i = w * 8 + q;
    const int gi = i0 + r_i;
    const float* rowp = &sc_s[r_i][0];
    float4 v0 = *(const float4*)(rowp + jb);
    float4 v1 = *(const float4*)(rowp + jb + 4);
    float sc[8] = {v0.x, v0.y, v0.z, v0.w, v1.x, v1.y, v1.z, v1.w};
#pragma unroll
    for (int c = 0; c < 8; ++c)
      if (jb + c >= jmax) sc[c] = -1e30f;  // beyond staged region (also masked)

    float m1 = sc[0];
#pragma unroll
    for (int c = 1; c < 8; ++c) m1 = fmaxf(m1, sc[c]);
    m1 = wave_max(m1);
    float p[8];
    float lsum = 0.0f;
#pragma unroll
    for (int c = 0; c < 8; ++c) {
      p[c] = expf(sc[c] - m1);   // masked: exp(-huge)=0
      lsum += p[c];
    }
    float tot = wave_sum(lsum);
    float inv = 1.0f / tot;

    float xs = lsum;
#pragma unroll
    for (int off = 1; off < 64; off <<= 1) {
      float y = __shfl_up(xs, off);
      if (lane >= off) xs += y;
    }
    float run = xs - lsum;

    float s2[8];
#pragma unroll
    for (int c = 0; c < 8; ++c) {
      run += p[c];
      float cum = run * inv;
      float dist = sqrtf(fmaxf((1.0f - cum) * (float)(gi - (jb + c)), 0.0f));
      float te = expf(gneg * dist);
      te = fminf(fmaxf(te, 1e-5f), 1e5f);
      s2[c] = sc[c] * te;
    }

    float m2 = s2[0];
#pragma unroll
    for (int c = 1; c < 8; ++c) m2 = fmaxf(m2, s2[c]);
    m2 = wave_max(m2);
    float e[8];
    float lsum2 = 0.0f;
#pragma unroll
    for (int c = 0; c < 8; ++c) {
      e[c] = expf(s2[c] - m2);
      lsum2 += e[c];
    }
    float tot2 = wave_sum(lsum2);
    float mult = fminf(tot2, 5.0f) / tot2;

    float av[8];
#pragma unroll
    for (int c = 0; c < 8; ++c) {
      av[c] = (gi == 0) ? 0.0f : e[c] * mult;
    }

    if (scores_out) {
      float* so = scores_out + ((size_t)(b * HH + h) * SS + gi) * SS + jb;
      *(float4*)(so) = make_float4(av[0], av[1], av[2], av[3]);
      *(float4*)(so + 4) = make_float4(av[4], av[5], av[6], av[7]);
    }

    // in-place bf16 write (row-local; reads above already consumed)
    short8 pk;
#pragma unroll
    for (int c = 0; c < 8; ++c) pk[c] = (short)f2bf(av[c]);
    *(short8*)((unsigned short*)&sc_s[r_i][0] + jb) = pk;
  }
  __syncthreads();

  // ---- PV: out[i,d] = sum_j attn[i,j] * V[j,d] ----
  f32x4 o0 = {}, o1 = {};
  for (int jt = 0; jt < njt; ++jt) {
    {
      const float* src = Vb + (size_t)(jt * 64 + srow) * DD + sdb;
      float4 f0 = *(const float4*)(src);
      float4 f1 = *(const float4*)(src + 4);
      Vt[sdb + 0][srow] = f2bf(f0.x);
      Vt[sdb + 1][srow] = f2bf(f0.y);
      Vt[sdb + 2][srow] = f2bf(f0.z);
      Vt[sdb + 3][srow] = f2bf(f0.w);
      Vt[sdb + 4][srow] = f2bf(f1.x);
      Vt[sdb + 5][srow] = f2bf(f1.y);
      Vt[sdb + 6][srow] = f2bf(f1.z);
      Vt[sdb + 7][srow] = f2bf(f1.w);
    }
    __syncthreads();

    const unsigned short* arow = (const unsigned short*)&sc_s[wr * 16 + fr][0];
    short8 a0 = *(const short8*)(arow + jt * 64 + fq * 8);
    short8 a1 = *(const short8*)(arow + jt * 64 + 32 + fq * 8);
    short8 b00 = *(const short8*)&Vt[wc * 32 + fr][fq * 8];
    short8 b01 = *(const short8*)&Vt[wc * 32 + fr][32 + fq * 8];
    short8 b10 = *(const short8*)&Vt[wc * 32 + 16 + fr][fq * 8];
    short8 b11 = *(const short8*)&Vt[wc * 32 + 16 + fr][32 + fq * 8];
    o0 = __builtin_amdgcn_mfma_f32_16x16x32_bf16(a0, b00, o0, 0, 0, 0);
    o0 = __builtin_amdgcn_mfma_f32_16x16x32_bf16(a1, b01, o0, 0, 0, 0);
    o1 = __builtin_amdgcn_mfma_f32_16x16x32_bf16(a0, b10, o1, 0, 0, 0);
    o1 = __builtin_amdgcn_mfma_f32_16x16x32_bf16(a1, b11, o1, 0, 0, 0);
    __syncthreads();
  }

#pragma unroll
  for (int n = 0; n < 2; ++n) {
    const int d = h * DHH + wc * 32 + n * 16 + fr;
#pragma unroll
    for (int r = 0; r < 4; ++r) {
      const int row = i0 + wr * 16 + fq * 4 + r;
      AO[((size_t)b * SS + row) * DD + d] = (n ? o1[r] : o0[r]);
    }
  }
}

// ---------------- residual + layernorm (r may be null) ----------------
__global__ __launch_bounds__(256) void k_res_ln(
    const float* __restrict__ x, const float* __restrict__ r,
    const float* __restrict__ w, const float* __restrict__ b,
    float* __restrict__ out) {
  __shared__ float red[4];
  const int row = blockIdx.x;
  const int tid = threadIdx.x;
  const int lane = tid & 63, wv = tid >> 6;
  float4 y = ((const float4*)(x + (size_t)row * DD))[tid];
  if (r) {
    float4 rr = ((const float4*)(r + (size_t)row * DD))[tid];
    y.x += rr.x; y.y += rr.y; y.z += rr.z; y.w += rr.w;
  }
  float s = y.x + y.y + y.z + y.w;
  s = wave_sum(s);
  if (lane == 0) red[wv] = s;
  __syncthreads();
  float mean = (red[0] + red[1] + red[2] + red[3]) * (1.0f / DD);
  __syncthreads();
  float d0 = y.x - mean, d1 = y.y - mean, d2 = y.z - mean, d3 = y.w - mean;
  float s2 = d0 * d0 + d1 * d1 + d2 * d2 + d3 * d3;
  s2 = wave_sum(s2);
  if (lane == 0) red[wv] = s2;
  __syncthreads();
  float var = (red[0] + red[1] + red[2] + red[3]) * (1.0f / DD);
  float rstd = rsqrtf(var + 1e-5f);
  float4 ww = ((const float4*)w)[tid];
  float4 bb = ((const float4*)b)[tid];
  float4 o;
  o.x = d0 * rstd * ww.x + bb.x;
  o.y = d1 * rstd * ww.y + bb.y;
  o.z = d2 * rstd * ww.z + bb.z;
  o.w = d3 * rstd * ww.w + bb.w;
  ((float4*)(out + (size_t)row * DD))[tid] = o;
}

extern "C" void kernel_launch(void* const* d_in, const int* in_sizes, int n_in,
                              void* d_out, int out_size, void* d_ws, size_t ws_size,
                              hipStream_t stream) {
  (void)in_sizes; (void)n_in; (void)out_size; (void)ws_size;
  const float* x = (const float*)d_in[0];
  const float* Wq = (const float*)d_in[2];
  const float* bq = (const float*)d_in[3];
  const float* Wv = (const float*)d_in[4];
  const float* bv = (const float*)d_in[5];
  const float* Wo = (const float*)d_in[6];
  const float* bo = (const float*)d_in[7];
  const float* gam = (const float*)d_in[8];
  const float* lnw = (const float*)d_in[9];
  const float* lnb = (const float*)d_in[10];
  const float* flnw = (const float*)d_in[11];
  const float* flnb = (const float*)d_in[12];

  float* out0 = (float*)d_out;
  float* scores = out0 + (size_t)BB * SS * DD;
  const size_t BUF = (size_t)BB * SS * DD;
  float* ws = (float*)d_ws;
  float* A = ws;
  float* t1 = ws + BUF;
  float* t2 = ws + 2 * BUF;
  float* t3 = out0;  // AO scratch lives in d_out region 0

  const int M = BB * SS;

  k_add_pe<<<dim3(BB * SS * DD / 256), 256, 0, stream>>>(x, A);

  for (int l = 0; l < LL; ++l) {
    const float* wq = Wq + (size_t)l * DD * DD;
    const float* wv_ = Wv + (size_t)l * DD * DD;
    const float* wo_ = Wo + (size_t)l * DD * DD;
    k_gemm_bt_bias<<<dim3(M / 64, DD / 64), 256, 0, stream>>>(A, wq, bq + l * DD, t1, M, DD, DD);
    k_gemm_bt_bias<<<dim3(M / 64, DD / 64), 256, 0, stream>>>(A, wv_, bv + l * DD, t2, M, DD, DD);
    k_attn_mfma<<<dim3(BB * HH * (SS / 64)), 512, 0, stream>>>(
        t1, t2, gam + l * HH, t3, (l == LL - 1) ? scores : nullptr);
    k_gemm_bt_bias<<<dim3(M / 64, DD / 64), 256, 0, stream>>>(t3, wo_, bo + l * DD, t1, M, DD, DD);
    k_res_ln<<<dim3(M), 256, 0, stream>>>(A, t1, lnw + l * DD, lnb + l * DD, t2);
    float* oldA = A; A = t2; t2 = t1; t1 = oldA;
  }
  k_res_ln<<<dim3(M), 256, 0, stream>>>(A, nullptr, flnw, flnb, out0);
}

// Round 3
// 1536.426 us; speedup vs baseline: 4.9547x; 1.2680x over previous
//
#include <hip/hip_runtime.h>
#include <hip/hip_bf16.h>

#define BB 16
#define SS 512
#define DD 1024
#define HH 16
#define LL 4
#define DHH 64

typedef __attribute__((ext_vector_type(8))) short short8;
typedef __attribute__((ext_vector_type(4))) float f32x4;

__device__ __forceinline__ unsigned short f2bf(float f) {
  union { float f; unsigned int u; } v; v.f = f;
  unsigned int r = v.u + 0x7FFFu + ((v.u >> 16) & 1u);
  return (unsigned short)(r >> 16);
}

__device__ __forceinline__ float wave_max(float v) {
#pragma unroll
  for (int off = 32; off > 0; off >>= 1) v = fmaxf(v, __shfl_xor(v, off));
  return v;
}
__device__ __forceinline__ float wave_sum(float v) {
#pragma unroll
  for (int off = 32; off > 0; off >>= 1) v += __shfl_xor(v, off);
  return v;
}

// ---------------- q0 = x + positional encoding ----------------
__global__ __launch_bounds__(256) void k_add_pe(const float* __restrict__ x,
                                                float* __restrict__ out) {
  size_t idx = (size_t)blockIdx.x * 256 + threadIdx.x;
  int d = (int)(idx & (DD - 1));
  int s = (int)((idx >> 10) & (SS - 1));
  int ip = d >> 1;
  float freq = __expf((float)ip * -0.017988946039016f);
  float ang = (float)s * freq;
  float pe = (d & 1) ? cosf(ang) : sinf(ang);
  out[idx] = x[idx] + pe;
}

// ---------------- C[M,N] = A[M,K] @ W[N,K]^T + bias, bf16 MFMA ----------------
__global__ __launch_bounds__(256) void k_gemm_bt_bias(
    const float* __restrict__ A, const float* __restrict__ W,
    const float* __restrict__ bias, float* __restrict__ C,
    int M, int N, int K) {
  __shared__ unsigned short As[64][40];
  __shared__ unsigned short Bs[64][40];
  const int tid = threadIdx.x;
  const int lane = tid & 63;
  const int w = tid >> 6;
  const int wr = w >> 1, wc = w & 1;
  const int bm = blockIdx.x * 64, bn = blockIdx.y * 64;
  const int lr = tid >> 2;
  const int lc = (tid & 3) << 3;
  const int fr = lane & 15, fq = lane >> 4;

  f32x4 acc[2][2] = {};

  const float* ag = A + (size_t)(bm + lr) * K + lc;
  const float* wg = W + (size_t)(bn + lr) * K + lc;

  for (int k0 = 0; k0 < K; k0 += 32) {
    float4 a0 = *(const float4*)(ag + k0);
    float4 a1 = *(const float4*)(ag + k0 + 4);
    float4 w0 = *(const float4*)(wg + k0);
    float4 w1 = *(const float4*)(wg + k0 + 4);
    short8 ap, wp;
    ap[0] = (short)f2bf(a0.x); ap[1] = (short)f2bf(a0.y);
    ap[2] = (short)f2bf(a0.z); ap[3] = (short)f2bf(a0.w);
    ap[4] = (short)f2bf(a1.x); ap[5] = (short)f2bf(a1.y);
    ap[6] = (short)f2bf(a1.z); ap[7] = (short)f2bf(a1.w);
    wp[0] = (short)f2bf(w0.x); wp[1] = (short)f2bf(w0.y);
    wp[2] = (short)f2bf(w0.z); wp[3] = (short)f2bf(w0.w);
    wp[4] = (short)f2bf(w1.x); wp[5] = (short)f2bf(w1.y);
    wp[6] = (short)f2bf(w1.z); wp[7] = (short)f2bf(w1.w);
    *(short8*)(&As[lr][lc]) = ap;
    *(short8*)(&Bs[lr][lc]) = wp;
    __syncthreads();

    short8 af0 = *(const short8*)(&As[wr * 32 + fr][fq * 8]);
    short8 af1 = *(const short8*)(&As[wr * 32 + 16 + fr][fq * 8]);
    short8 bf0 = *(const short8*)(&Bs[wc * 32 + fr][fq * 8]);
    short8 bf1 = *(const short8*)(&Bs[wc * 32 + 16 + fr][fq * 8]);
    acc[0][0] = __builtin_amdgcn_mfma_f32_16x16x32_bf16(af0, bf0, acc[0][0], 0, 0, 0);
    acc[0][1] = __builtin_amdgcn_mfma_f32_16x16x32_bf16(af0, bf1, acc[0][1], 0, 0, 0);
    acc[1][0] = __builtin_amdgcn_mfma_f32_16x16x32_bf16(af1, bf0, acc[1][0], 0, 0, 0);
    acc[1][1] = __builtin_amdgcn_mfma_f32_16x16x32_bf16(af1, bf1, acc[1][1], 0, 0, 0);
    __syncthreads();
  }

#pragma unroll
  for (int m = 0; m < 2; ++m)
#pragma unroll
    for (int n = 0; n < 2; ++n) {
      int row = bm + wr * 32 + m * 16 + fq * 4;
      int col = bn + wc * 32 + n * 16 + fr;
      float bb = bias[col];
#pragma unroll
      for (int r = 0; r < 4; ++r)
        C[(size_t)(row + r) * N + col] = acc[m][n][r] + bb;
    }
}

// ---------------- fused MFMA attention ----------------
// Block: one (b,h), 32-row i-tile, 8 waves (512 thr). LDS 79.4 KB -> 2 blk/CU.
// QK^T phase: wave grid 2x4 (wr rows, wc 16-col block) over 64-col j-tiles.
// K tile and V^T tile share one union buffer (disjoint phases).
// Full fp32 score rows in LDS (chain needs whole row); attn re-written
// in place as bf16 to feed PV A-fragments.
__global__ __launch_bounds__(512) void k_attn_mfma(
    const float* __restrict__ QK, const float* __restrict__ V,
    const float* __restrict__ gam, float* __restrict__ AO,
    float* __restrict__ scores_out) {
  __shared__ float sc_s[32][516];          // 66048 B
  __shared__ unsigned short Qs[32][72];    //  4608 B
  __shared__ unsigned short KV[64][68];    //  8704 B (K tile, then V^T tile)

  const int tid = threadIdx.x;
  const int lane = tid & 63;
  const int w = tid >> 6;
  const int wr = w & 1;        // 16-row half
  const int wc = w >> 1;       // 16-col quarter
  const int fr = lane & 15, fq = lane >> 4;

  const int itile = blockIdx.x & 15;
  const int bh = blockIdx.x >> 4;
  const int b = bh >> 4;
  const int h = bh & 15;
  const int i0 = itile * 32;
  const int njt = (itile + 2) >> 1;        // 64-col j-tiles covering j <= i0+30
  const int jcap = njt * 64;

  const float* Qb = QK + (size_t)b * SS * DD + (size_t)h * DHH;
  const float* Vb = V + (size_t)b * SS * DD + (size_t)h * DHH;
  const float gneg = -fabsf(gam[h]);

  const int srow = tid >> 3;             // 0..63 staging row (K/V tiles)
  const int sdb = (tid & 7) * 8;         // staging d-block

  // stage Q tile (32 rows x 64 d, bf16): thread -> 4 floats
  {
    const int qrow = tid >> 4;           // 0..31
    const int qc = (tid & 15) * 4;       // 0..60
    float4 f0 = *(const float4*)(Qb + (size_t)(i0 + qrow) * DD + qc);
    unsigned short p0 = f2bf(f0.x), p1 = f2bf(f0.y), p2 = f2bf(f0.z), p3 = f2bf(f0.w);
    unsigned int lo = (unsigned int)p0 | ((unsigned int)p1 << 16);
    unsigned int hi = (unsigned int)p2 | ((unsigned int)p3 << 16);
    *(uint2*)&Qs[qrow][qc] = make_uint2(lo, hi);
  }

  // ---- QK^T into sc_s (scaled + causally masked) ----
  for (int jt = 0; jt < njt; ++jt) {
    {
      const float* src = Qb + (size_t)(jt * 64 + srow) * DD + sdb;  // K == Q
      float4 f0 = *(const float4*)(src);
      float4 f1 = *(const float4*)(src + 4);
      short8 pk;
      pk[0] = (short)f2bf(f0.x); pk[1] = (short)f2bf(f0.y);
      pk[2] = (short)f2bf(f0.z); pk[3] = (short)f2bf(f0.w);
      pk[4] = (short)f2bf(f1.x); pk[5] = (short)f2bf(f1.y);
      pk[6] = (short)f2bf(f1.z); pk[7] = (short)f2bf(f1.w);
      *(short8*)&KV[srow][sdb] = pk;
    }
    __syncthreads();

    short8 a0 = *(const short8*)&Qs[wr * 16 + fr][fq * 8];
    short8 a1 = *(const short8*)&Qs[wr * 16 + fr][32 + fq * 8];
    short8 b0 = *(const short8*)&KV[wc * 16 + fr][fq * 8];
    short8 b1 = *(const short8*)&KV[wc * 16 + fr][32 + fq * 8];
    f32x4 s0 = {};
    s0 = __builtin_amdgcn_mfma_f32_16x16x32_bf16(a0, b0, s0, 0, 0, 0);
    s0 = __builtin_amdgcn_mfma_f32_16x16x32_bf16(a1, b1, s0, 0, 0, 0);

    const int j = jt * 64 + wc * 16 + fr;
#pragma unroll
    for (int r = 0; r < 4; ++r) {
      const int row = wr * 16 + fq * 4 + r;
      sc_s[row][j] = (j < i0 + row) ? s0[r] * 0.125f : -1e30f;
    }
    __syncthreads();
  }

  // ---- softmax -> cumsum -> dist-decay -> softmax -> maxout, per row ----
  // wave w handles rows w*4 .. w*4+3
  const int jb = lane << 3;
  for (int q = 0; q < 4; ++q) {
    const int r_i = w * 4 + q;
    const int gi = i0 + r_i;
    const float* rowp = &sc_s[r_i][0];
    float4 v0 = *(const float4*)(rowp + jb);
    float4 v1 = *(const float4*)(rowp + jb + 4);
    float sc[8] = {v0.x, v0.y, v0.z, v0.w, v1.x, v1.y, v1.z, v1.w};
#pragma unroll
    for (int c = 0; c < 8; ++c)
      if (jb + c >= jcap) sc[c] = -1e30f;  // beyond staged region

    float m1 = sc[0];
#pragma unroll
    for (int c = 1; c < 8; ++c) m1 = fmaxf(m1, sc[c]);
    m1 = wave_max(m1);
    float p[8];
    float lsum = 0.0f;
#pragma unroll
    for (int c = 0; c < 8; ++c) {
      p[c] = __expf(sc[c] - m1);   // masked: exp(-huge)=0
      lsum += p[c];
    }
    float tot = wave_sum(lsum);
    float inv = 1.0f / tot;

    float xs = lsum;
#pragma unroll
    for (int off = 1; off < 64; off <<= 1) {
      float y = __shfl_up(xs, off);
      if (lane >= off) xs += y;
    }
    float run = xs - lsum;

    float s2[8];
#pragma unroll
    for (int c = 0; c < 8; ++c) {
      run += p[c];
      float cum = run * inv;
      float dist = sqrtf(fmaxf((1.0f - cum) * (float)(gi - (jb + c)), 0.0f));
      float te = __expf(gneg * dist);
      te = fminf(fmaxf(te, 1e-5f), 1e5f);
      s2[c] = sc[c] * te;
    }

    float m2 = s2[0];
#pragma unroll
    for (int c = 1; c < 8; ++c) m2 = fmaxf(m2, s2[c]);
    m2 = wave_max(m2);
    float e[8];
    float lsum2 = 0.0f;
#pragma unroll
    for (int c = 0; c < 8; ++c) {
      e[c] = __expf(s2[c] - m2);
      lsum2 += e[c];
    }
    float tot2 = wave_sum(lsum2);
    float mult = fminf(tot2, 5.0f) / tot2;

    float av[8];
#pragma unroll
    for (int c = 0; c < 8; ++c) {
      av[c] = (gi == 0) ? 0.0f : e[c] * mult;
    }

    if (scores_out) {
      float* so = scores_out + ((size_t)(b * HH + h) * SS + gi) * SS + jb;
      *(float4*)(so) = make_float4(av[0], av[1], av[2], av[3]);
      *(float4*)(so + 4) = make_float4(av[4], av[5], av[6], av[7]);
    }

    // in-place bf16 write (row-local; reads above already consumed)
    short8 pk;
#pragma unroll
    for (int c = 0; c < 8; ++c) pk[c] = (short)f2bf(av[c]);
    *(short8*)((unsigned short*)&sc_s[r_i][0] + jb) = pk;
  }
  __syncthreads();

  // ---- PV: out[i,d] = sum_j attn[i,j] * V[j,d]; V^T staged into KV ----
  f32x4 o0 = {};
  for (int jt = 0; jt < njt; ++jt) {
    {
      const float* src = Vb + (size_t)(jt * 64 + srow) * DD + sdb;
      float4 f0 = *(const float4*)(src);
      float4 f1 = *(const float4*)(src + 4);
      KV[sdb + 0][srow] = f2bf(f0.x);
      KV[sdb + 1][srow] = f2bf(f0.y);
      KV[sdb + 2][srow] = f2bf(f0.z);
      KV[sdb + 3][srow] = f2bf(f0.w);
      KV[sdb + 4][srow] = f2bf(f1.x);
      KV[sdb + 5][srow] = f2bf(f1.y);
      KV[sdb + 6][srow] = f2bf(f1.z);
      KV[sdb + 7][srow] = f2bf(f1.w);
    }
    __syncthreads();

    const unsigned short* arow = (const unsigned short*)&sc_s[wr * 16 + fr][0];
    short8 a0 = *(const short8*)(arow + jt * 64 + fq * 8);
    short8 a1 = *(const short8*)(arow + jt * 64 + 32 + fq * 8);
    short8 b0 = *(const short8*)&KV[wc * 16 + fr][fq * 8];
    short8 b1 = *(const short8*)&KV[wc * 16 + fr][32 + fq * 8];
    o0 = __builtin_amdgcn_mfma_f32_16x16x32_bf16(a0, b0, o0, 0, 0, 0);
    o0 = __builtin_amdgcn_mfma_f32_16x16x32_bf16(a1, b1, o0, 0, 0, 0);
    __syncthreads();
  }

  {
    const int d = h * DHH + wc * 16 + fr;
#pragma unroll
    for (int r = 0; r < 4; ++r) {
      const int row = i0 + wr * 16 + fq * 4 + r;
      AO[((size_t)b * SS + row) * DD + d] = o0[r];
    }
  }
}

// ---------------- residual + layernorm (r may be null) ----------------
__global__ __launch_bounds__(256) void k_res_ln(
    const float* __restrict__ x, const float* __restrict__ r,
    const float* __restrict__ w, const float* __restrict__ b,
    float* __restrict__ out) {
  __shared__ float red[4];
  const int row = blockIdx.x;
  const int tid = threadIdx.x;
  const int lane = tid & 63, wv = tid >> 6;
  float4 y = ((const float4*)(x + (size_t)row * DD))[tid];
  if (r) {
    float4 rr = ((const float4*)(r + (size_t)row * DD))[tid];
    y.x += rr.x; y.y += rr.y; y.z += rr.z; y.w += rr.w;
  }
  float s = y.x + y.y + y.z + y.w;
  s = wave_sum(s);
  if (lane == 0) red[wv] = s;
  __syncthreads();
  float mean = (red[0] + red[1] + red[2] + red[3]) * (1.0f / DD);
  __syncthreads();
  float d0 = y.x - mean, d1 = y.y - mean, d2 = y.z - mean, d3 = y.w - mean;
  float s2 = d0 * d0 + d1 * d1 + d2 * d2 + d3 * d3;
  s2 = wave_sum(s2);
  if (lane == 0) red[wv] = s2;
  __syncthreads();
  float var = (red[0] + red[1] + red[2] + red[3]) * (1.0f / DD);
  float rstd = rsqrtf(var + 1e-5f);
  float4 ww = ((const float4*)w)[tid];
  float4 bb = ((const float4*)b)[tid];
  float4 o;
  o.x = d0 * rstd * ww.x + bb.x;
  o.y = d1 * rstd * ww.y + bb.y;
  o.z = d2 * rstd * ww.z + bb.z;
  o.w = d3 * rstd * ww.w + bb.w;
  ((float4*)(out + (size_t)row * DD))[tid] = o;
}

extern "C" void kernel_launch(void* const* d_in, const int* in_sizes, int n_in,
                              void* d_out, int out_size, void* d_ws, size_t ws_size,
                              hipStream_t stream) {
  (void)in_sizes; (void)n_in; (void)out_size; (void)ws_size;
  const float* x = (const float*)d_in[0];
  const float* Wq = (const float*)d_in[2];
  const float* bq = (const float*)d_in[3];
  const float* Wv = (const float*)d_in[4];
  const float* bv = (const float*)d_in[5];
  const float* Wo = (const float*)d_in[6];
  const float* bo = (const float*)d_in[7];
  const float* gam = (const float*)d_in[8];
  const float* lnw = (const float*)d_in[9];
  const float* lnb = (const float*)d_in[10];
  const float* flnw = (const float*)d_in[11];
  const float* flnb = (const float*)d_in[12];

  float* out0 = (float*)d_out;
  float* scores = out0 + (size_t)BB * SS * DD;
  const size_t BUF = (size_t)BB * SS * DD;
  float* ws = (float*)d_ws;
  float* A = ws;
  float* t1 = ws + BUF;
  float* t2 = ws + 2 * BUF;
  float* t3 = out0;  // AO scratch lives in d_out region 0

  const int M = BB * SS;

  k_add_pe<<<dim3(BB * SS * DD / 256), 256, 0, stream>>>(x, A);

  for (int l = 0; l < LL; ++l) {
    const float* wq = Wq + (size_t)l * DD * DD;
    const float* wv_ = Wv + (size_t)l * DD * DD;
    const float* wo_ = Wo + (size_t)l * DD * DD;
    k_gemm_bt_bias<<<dim3(M / 64, DD / 64), 256, 0, stream>>>(A, wq, bq + l * DD, t1, M, DD, DD);
    k_gemm_bt_bias<<<dim3(M / 64, DD / 64), 256, 0, stream>>>(A, wv_, bv + l * DD, t2, M, DD, DD);
    k_attn_mfma<<<dim3(BB * HH * (SS / 32)), 512, 0, stream>>>(
        t1, t2, gam + l * HH, t3, (l == LL - 1) ? scores : nullptr);
    k_gemm_bt_bias<<<dim3(M / 64, DD / 64), 256, 0, stream>>>(t3, wo_, bo + l * DD, t1, M, DD, DD);
    k_res_ln<<<dim3(M), 256, 0, stream>>>(A, t1, lnw + l * DD, lnb + l * DD, t2);
    float* oldA = A; A = t2; t2 = t1; t1 = oldA;
  }
  k_res_ln<<<dim3(M), 256, 0, stream>>>(A, nullptr, flnw, flnb, out0);
}

// Round 4
// 1113.944 us; speedup vs baseline: 6.8338x; 1.3793x over previous
//
#include <hip/hip_runtime.h>
#include <hip/hip_bf16.h>

#define BB 16
#define SS 512
#define DD 1024
#define HH 16
#define LL 4
#define DHH 64
#define GK 1024
#define GN 1024

typedef __attribute__((ext_vector_type(8))) short short8;
typedef __attribute__((ext_vector_type(4))) float f32x4;

__device__ __forceinline__ unsigned short f2bf(float f) {
  union { float f; unsigned int u; } v; v.f = f;
  unsigned int r = v.u + 0x7FFFu + ((v.u >> 16) & 1u);
  return (unsigned short)(r >> 16);
}

__device__ __forceinline__ float wave_max(float v) {
#pragma unroll
  for (int off = 32; off > 0; off >>= 1) v = fmaxf(v, __shfl_xor(v, off));
  return v;
}
__device__ __forceinline__ float wave_sum(float v) {
#pragma unroll
  for (int off = 32; off > 0; off >>= 1) v += __shfl_xor(v, off);
  return v;
}

// global -> LDS direct 16B copy (CK-style addrspace reinterpret).
// LDS dest is wave-uniform base + lane*16 (per-lane dest bits ignored).
__device__ __forceinline__ void gl16(const void* g, void* l) {
  __builtin_amdgcn_global_load_lds(
      (const __attribute__((address_space(1))) unsigned int*)(uintptr_t)g,
      (__attribute__((address_space(3))) unsigned int*)(unsigned int)(uintptr_t)l,
      16, 0, 0);
}

// ---------------- weights fp32 -> bf16 ----------------
__global__ __launch_bounds__(256) void k_w2bf(const float* __restrict__ w,
                                              unsigned short* __restrict__ o) {
  size_t i4 = ((size_t)blockIdx.x * 256 + threadIdx.x) * 4;
  float4 v = *(const float4*)(w + i4);
  uint2 pk;
  pk.x = (unsigned)f2bf(v.x) | ((unsigned)f2bf(v.y) << 16);
  pk.y = (unsigned)f2bf(v.z) | ((unsigned)f2bf(v.w) << 16);
  *(uint2*)(o + i4) = pk;
}

// ---------------- q0 = x + positional encoding (fp32 + bf16 shadow) ----------------
__global__ __launch_bounds__(256) void k_add_pe(const float* __restrict__ x,
                                                float* __restrict__ out,
                                                unsigned short* __restrict__ outb) {
  size_t i4 = ((size_t)blockIdx.x * 256 + threadIdx.x) * 4;
  int d0 = (int)(i4 & (DD - 1));
  int s = (int)((i4 >> 10) & (SS - 1));
  float4 xv = *(const float4*)(x + i4);
  int ip0 = d0 >> 1;
  float f0 = __expf((float)ip0 * -0.017988946039016f);
  float f1 = __expf((float)(ip0 + 1) * -0.017988946039016f);
  float s0v, c0v, s1v, c1v;
  __sincosf((float)s * f0, &s0v, &c0v);
  __sincosf((float)s * f1, &s1v, &c1v);
  float4 o;
  o.x = xv.x + s0v; o.y = xv.y + c0v; o.z = xv.z + s1v; o.w = xv.w + c1v;
  *(float4*)(out + i4) = o;
  uint2 pk;
  pk.x = (unsigned)f2bf(o.x) | ((unsigned)f2bf(o.y) << 16);
  pk.y = (unsigned)f2bf(o.z) | ((unsigned)f2bf(o.w) << 16);
  *(uint2*)(outb + i4) = pk;
}

// ---------------- C = A[M,K]bf16 @ W[N,K]^T bf16 + bias ----------------
// m97 structure: 128x128 tile, 4 waves (2x2), BK=32, global_load_lds 16B.
// MODE 0: bf16 [M,N] out.  MODE 1: bf16 transposed [b, col, s] out.  MODE 2: fp32 [M,N].
template <int MODE>
__global__ __launch_bounds__(256) void k_gemm(
    const unsigned short* __restrict__ A, const unsigned short* __restrict__ W,
    const float* __restrict__ bias, void* __restrict__ out) {
  __shared__ unsigned short As[128 * 32];
  __shared__ unsigned short Bs[128 * 32];
  const int tid = threadIdx.x;
  const int lane = tid & 63;
  const int w = tid >> 6;
  const int wr = w >> 1, wc = w & 1;
  const int fr = lane & 15, fq = lane >> 4;

  // XCD swizzle: 512 wgs = 8 XCDs x 64; each XCD owns one N-panel sweep
  int bid = blockIdx.x;
  bid = (bid & 7) * 64 + (bid >> 3);
  const int bm = (bid & 63) * 128;
  const int bn = (bid >> 6) * 128;

  f32x4 acc[4][4] = {};

  const unsigned short* ga = A + (size_t)(bm + w * 16 + (lane >> 2)) * GK + (lane & 3) * 8;
  const unsigned short* gb = W + (size_t)(bn + w * 16 + (lane >> 2)) * GK + (lane & 3) * 8;
  unsigned short* la = As + w * 512;   // wave-uniform LDS base
  unsigned short* lb = Bs + w * 512;

  for (int k0 = 0; k0 < GK; k0 += 32) {
    gl16(ga + k0, la);
    gl16(ga + 64 * GK + k0, la + 2048);
    gl16(gb + k0, lb);
    gl16(gb + 64 * GK + k0, lb + 2048);
    __syncthreads();
    short8 af[4], bf[4];
#pragma unroll
    for (int m = 0; m < 4; ++m)
      af[m] = *(const short8*)(As + (wr * 64 + m * 16 + fr) * 32 + fq * 8);
#pragma unroll
    for (int n = 0; n < 4; ++n)
      bf[n] = *(const short8*)(Bs + (wc * 64 + n * 16 + fr) * 32 + fq * 8);
#pragma unroll
    for (int m = 0; m < 4; ++m)
#pragma unroll
      for (int n = 0; n < 4; ++n)
        acc[m][n] = __builtin_amdgcn_mfma_f32_16x16x32_bf16(af[m], bf[n], acc[m][n], 0, 0, 0);
    __syncthreads();
  }

#pragma unroll
  for (int m = 0; m < 4; ++m) {
    const int row0 = bm + wr * 64 + m * 16 + fq * 4;
#pragma unroll
    for (int n = 0; n < 4; ++n) {
      const int col = bn + wc * 64 + n * 16 + fr;
      const float bsv = bias[col];
      if constexpr (MODE == 0) {
        unsigned short* o = (unsigned short*)out;
#pragma unroll
        for (int r = 0; r < 4; ++r)
          o[(size_t)(row0 + r) * GN + col] = f2bf(acc[m][n][r] + bsv);
      } else if constexpr (MODE == 1) {
        unsigned short* o = (unsigned short*)out;
        const int bi = row0 >> 9, si = row0 & (SS - 1);
        uint2 pk;
        pk.x = (unsigned)f2bf(acc[m][n][0] + bsv) | ((unsigned)f2bf(acc[m][n][1] + bsv) << 16);
        pk.y = (unsigned)f2bf(acc[m][n][2] + bsv) | ((unsigned)f2bf(acc[m][n][3] + bsv) << 16);
        *(uint2*)(o + ((size_t)bi * DD + col) * SS + si) = pk;
      } else {
        float* o = (float*)out;
#pragma unroll
        for (int r = 0; r < 4; ++r)
          o[(size_t)(row0 + r) * GN + col] = acc[m][n][r] + bsv;
      }
    }
  }
}

// ---------------- fused MFMA attention (bf16 inputs) ----------------
// Block: one (b,h), 32-row i-tile, 8 waves. Q/K from bf16 qlin [b,s,D];
// V from transposed bf16 Vt [b, dcol, s] (no in-kernel transpose).
// LDS 78 KB -> 2 blocks/CU. Scores fp32 in LDS for the full
// softmax->cumsum->dist->softmax->maxout chain; attn rewritten in place
// as bf16 to feed PV A-fragments.
__global__ __launch_bounds__(512) void k_attn_mfma(
    const unsigned short* __restrict__ Q, const unsigned short* __restrict__ Vt,
    const float* __restrict__ gam, unsigned short* __restrict__ AO,
    float* __restrict__ scores_out) {
  __shared__ float sc_s[32][516];          // 66048 B
  __shared__ unsigned short Qs[32][72];    //  4608 B
  __shared__ unsigned short KV[64][72];    //  9216 B (K tile, then V^T tile)

  const int tid = threadIdx.x;
  const int lane = tid & 63;
  const int w = tid >> 6;
  const int wr = w & 1;
  const int wc = w >> 1;
  const int fr = lane & 15, fq = lane >> 4;

  const int itile = blockIdx.x & 15;
  const int bh = blockIdx.x >> 4;
  const int b = bh >> 4;
  const int h = bh & 15;
  const int i0 = itile * 32;
  const int njt = (itile + 2) >> 1;
  const int jcap = njt * 64;

  const unsigned short* Qb = Q + (size_t)b * SS * DD + h * DHH;
  const unsigned short* Vtb = Vt + ((size_t)b * DD + h * DHH) * SS;
  const float gneg = -fabsf(gam[h]);

  const int srow = tid >> 3;             // 0..63
  const int sdb = (tid & 7) * 8;

  if (tid < 256) {
    const int qr = tid >> 3, qc = (tid & 7) * 8;
    *(short8*)&Qs[qr][qc] = *(const short8*)(Qb + (size_t)(i0 + qr) * DD + qc);
  }

  // ---- QK^T into sc_s (scaled + causally masked) ----
  for (int jt = 0; jt < njt; ++jt) {
    *(short8*)&KV[srow][sdb] = *(const short8*)(Qb + (size_t)(jt * 64 + srow) * DD + sdb);
    __syncthreads();

    short8 a0 = *(const short8*)&Qs[wr * 16 + fr][fq * 8];
    short8 a1 = *(const short8*)&Qs[wr * 16 + fr][32 + fq * 8];
    short8 b0 = *(const short8*)&KV[wc * 16 + fr][fq * 8];
    short8 b1 = *(const short8*)&KV[wc * 16 + fr][32 + fq * 8];
    f32x4 s0 = {};
    s0 = __builtin_amdgcn_mfma_f32_16x16x32_bf16(a0, b0, s0, 0, 0, 0);
    s0 = __builtin_amdgcn_mfma_f32_16x16x32_bf16(a1, b1, s0, 0, 0, 0);

    const int j = jt * 64 + wc * 16 + fr;
#pragma unroll
    for (int r = 0; r < 4; ++r) {
      const int row = wr * 16 + fq * 4 + r;
      sc_s[row][j] = (j < i0 + row) ? s0[r] * 0.125f : -1e30f;
    }
    __syncthreads();
  }

  // ---- softmax -> cumsum -> dist-decay -> softmax -> maxout, per row ----
  const int jb = lane << 3;
  for (int q = 0; q < 4; ++q) {
    const int r_i = w * 4 + q;
    const int gi = i0 + r_i;
    const float* rowp = &sc_s[r_i][0];
    float4 v0 = *(const float4*)(rowp + jb);
    float4 v1 = *(const float4*)(rowp + jb + 4);
    float sc[8] = {v0.x, v0.y, v0.z, v0.w, v1.x, v1.y, v1.z, v1.w};
#pragma unroll
    for (int c = 0; c < 8; ++c)
      if (jb + c >= jcap) sc[c] = -1e30f;

    float m1 = sc[0];
#pragma unroll
    for (int c = 1; c < 8; ++c) m1 = fmaxf(m1, sc[c]);
    m1 = wave_max(m1);
    float p[8];
    float lsum = 0.0f;
#pragma unroll
    for (int c = 0; c < 8; ++c) {
      p[c] = __expf(sc[c] - m1);
      lsum += p[c];
    }
    float tot = wave_sum(lsum);
    float inv = 1.0f / tot;

    float xs = lsum;
#pragma unroll
    for (int off = 1; off < 64; off <<= 1) {
      float y = __shfl_up(xs, off);
      if (lane >= off) xs += y;
    }
    float run = xs - lsum;

    float s2[8];
#pragma unroll
    for (int c = 0; c < 8; ++c) {
      run += p[c];
      float cum = run * inv;
      float dist = sqrtf(fmaxf((1.0f - cum) * (float)(gi - (jb + c)), 0.0f));
      float te = __expf(gneg * dist);
      te = fminf(fmaxf(te, 1e-5f), 1e5f);
      s2[c] = sc[c] * te;
    }

    float m2 = s2[0];
#pragma unroll
    for (int c = 1; c < 8; ++c) m2 = fmaxf(m2, s2[c]);
    m2 = wave_max(m2);
    float e[8];
    float lsum2 = 0.0f;
#pragma unroll
    for (int c = 0; c < 8; ++c) {
      e[c] = __expf(s2[c] - m2);
      lsum2 += e[c];
    }
    float tot2 = wave_sum(lsum2);
    float mult = fminf(tot2, 5.0f) / tot2;

    float av[8];
#pragma unroll
    for (int c = 0; c < 8; ++c) {
      av[c] = (gi == 0) ? 0.0f : e[c] * mult;
    }

    if (scores_out) {
      float* so = scores_out + ((size_t)(b * HH + h) * SS + gi) * SS + jb;
      *(float4*)(so) = make_float4(av[0], av[1], av[2], av[3]);
      *(float4*)(so + 4) = make_float4(av[4], av[5], av[6], av[7]);
    }

    short8 pk;
#pragma unroll
    for (int c = 0; c < 8; ++c) pk[c] = (short)f2bf(av[c]);
    *(short8*)((unsigned short*)&sc_s[r_i][0] + jb) = pk;
  }
  __syncthreads();

  // ---- PV: out[i,d] = sum_j attn[i,j] * V[j,d]; V^T tile from Vt global ----
  f32x4 o0 = {};
  for (int jt = 0; jt < njt; ++jt) {
    *(short8*)&KV[srow][sdb] =
        *(const short8*)(Vtb + (size_t)srow * SS + jt * 64 + sdb);
    __syncthreads();

    const unsigned short* arow = (const unsigned short*)&sc_s[wr * 16 + fr][0];
    short8 a0 = *(const short8*)(arow + jt * 64 + fq * 8);
    short8 a1 = *(const short8*)(arow + jt * 64 + 32 + fq * 8);
    short8 b0 = *(const short8*)&KV[wc * 16 + fr][fq * 8];
    short8 b1 = *(const short8*)&KV[wc * 16 + fr][32 + fq * 8];
    o0 = __builtin_amdgcn_mfma_f32_16x16x32_bf16(a0, b0, o0, 0, 0, 0);
    o0 = __builtin_amdgcn_mfma_f32_16x16x32_bf16(a1, b1, o0, 0, 0, 0);
    __syncthreads();
  }

  {
    const int d = h * DHH + wc * 16 + fr;
#pragma unroll
    for (int r = 0; r < 4; ++r) {
      const int row = i0 + wr * 16 + fq * 4 + r;
      AO[((size_t)b * SS + row) * DD + d] = f2bf(o0[r]);
    }
  }
}

// ---------------- residual + layernorm (fp32 out, optional bf16 shadow) ----------------
__global__ __launch_bounds__(256) void k_res_ln(
    const float* __restrict__ x, const float* __restrict__ r,
    const float* __restrict__ w, const float* __restrict__ b,
    float* __restrict__ out, unsigned short* __restrict__ outb) {
  __shared__ float red[4];
  const int row = blockIdx.x;
  const int tid = threadIdx.x;
  const int lane = tid & 63, wv = tid >> 6;
  float4 y = ((const float4*)(x + (size_t)row * DD))[tid];
  if (r) {
    float4 rr = ((const float4*)(r + (size_t)row * DD))[tid];
    y.x += rr.x; y.y += rr.y; y.z += rr.z; y.w += rr.w;
  }
  float s = y.x + y.y + y.z + y.w;
  s = wave_sum(s);
  if (lane == 0) red[wv] = s;
  __syncthreads();
  float mean = (red[0] + red[1] + red[2] + red[3]) * (1.0f / DD);
  __syncthreads();
  float d0 = y.x - mean, d1 = y.y - mean, d2 = y.z - mean, d3 = y.w - mean;
  float s2 = d0 * d0 + d1 * d1 + d2 * d2 + d3 * d3;
  s2 = wave_sum(s2);
  if (lane == 0) red[wv] = s2;
  __syncthreads();
  float var = (red[0] + red[1] + red[2] + red[3]) * (1.0f / DD);
  float rstd = rsqrtf(var + 1e-5f);
  float4 ww = ((const float4*)w)[tid];
  float4 bb = ((const float4*)b)[tid];
  float4 o;
  o.x = d0 * rstd * ww.x + bb.x;
  o.y = d1 * rstd * ww.y + bb.y;
  o.z = d2 * rstd * ww.z + bb.z;
  o.w = d3 * rstd * ww.w + bb.w;
  ((float4*)(out + (size_t)row * DD))[tid] = o;
  if (outb) {
    uint2 pk;
    pk.x = (unsigned)f2bf(o.x) | ((unsigned)f2bf(o.y) << 16);
    pk.y = (unsigned)f2bf(o.z) | ((unsigned)f2bf(o.w) << 16);
    *(uint2*)(outb + (size_t)row * DD + tid * 4) = pk;
  }
}

extern "C" void kernel_launch(void* const* d_in, const int* in_sizes, int n_in,
                              void* d_out, int out_size, void* d_ws, size_t ws_size,
                              hipStream_t stream) {
  (void)in_sizes; (void)n_in; (void)out_size; (void)ws_size;
  const float* x = (const float*)d_in[0];
  const float* Wq = (const float*)d_in[2];
  const float* bq = (const float*)d_in[3];
  const float* Wv = (const float*)d_in[4];
  const float* bv = (const float*)d_in[5];
  const float* Wo = (const float*)d_in[6];
  const float* bo = (const float*)d_in[7];
  const float* gam = (const float*)d_in[8];
  const float* lnw = (const float*)d_in[9];
  const float* lnb = (const float*)d_in[10];
  const float* flnw = (const float*)d_in[11];
  const float* flnb = (const float*)d_in[12];

  float* out0 = (float*)d_out;
  float* scores = out0 + (size_t)BB * SS * DD;
  const size_t BUF = (size_t)BB * SS * DD;       // 8.4M elems
  const size_t WSZ = (size_t)LL * DD * DD;       // 4.2M elems per weight set
  const size_t BHSS = (size_t)BB * HH * SS * SS; // 67.1M floats (scores)

  float* P0 = (float*)d_ws;
  float* P1 = P0 + BUF;
  unsigned short* us = (unsigned short*)(P1 + BUF);
  unsigned short* Abf = us;
  unsigned short* Qbf = us + BUF;
  unsigned short* VtB = us + 2 * BUF;
  unsigned short* AObf = us + 3 * BUF;
  unsigned short* Wob = us + 4 * BUF;            // ws total ~142.6 MB
  // Wq/Wv bf16 live at the tail of the scores region of d_out: their last
  // use (layer-3 q/v GEMMs) precedes the layer-3 attention that overwrites
  // the whole scores region with the real output.
  unsigned short* Wqb = (unsigned short*)scores + (2 * BHSS - 2 * WSZ);
  unsigned short* Wvb = Wqb + WSZ;

  const int M = BB * SS;  // 8192

  k_w2bf<<<dim3(WSZ / 1024), 256, 0, stream>>>(Wq, Wqb);
  k_w2bf<<<dim3(WSZ / 1024), 256, 0, stream>>>(Wv, Wvb);
  k_w2bf<<<dim3(WSZ / 1024), 256, 0, stream>>>(Wo, Wob);
  k_add_pe<<<dim3(BUF / 1024), 256, 0, stream>>>(x, P0, Abf);

  float* Acur = P0;
  float* Pnx = P1;
  for (int l = 0; l < LL; ++l) {
    k_gemm<0><<<dim3(512), 256, 0, stream>>>(Abf, Wqb + (size_t)l * DD * DD, bq + l * DD, Qbf);
    k_gemm<1><<<dim3(512), 256, 0, stream>>>(Abf, Wvb + (size_t)l * DD * DD, bv + l * DD, VtB);
    k_attn_mfma<<<dim3(BB * HH * (SS / 32)), 512, 0, stream>>>(
        Qbf, VtB, gam + l * HH, AObf, (l == LL - 1) ? scores : nullptr);
    k_gemm<2><<<dim3(512), 256, 0, stream>>>(AObf, Wob + (size_t)l * DD * DD, bo + l * DD, Pnx);
    k_res_ln<<<dim3(M), 256, 0, stream>>>(Acur, Pnx, lnw + l * DD, lnb + l * DD, Pnx, Abf);
    float* t = Acur; Acur = Pnx; Pnx = t;
  }
  k_res_ln<<<dim3(M), 256, 0, stream>>>(Acur, nullptr, flnw, flnb, out0, nullptr);
}